// Round 11
// baseline (16.690 us; speedup 1.0000x reference)
//
#include <hip/hip_runtime.h>

// Euler characteristic curve of sublevel cubical complex.
// x: [B,C,H,W] f32 -> out: [B,C,RES] f32.
//
// R9 scaffold + lower-star inner loop (1 LDS atomic per vertex, was 4):
//   - every cell's filtration value = value of its max vertex; assign each
//     cell to that vertex (tie: larger linear index owns; so smaller-index
//     neighbors use <=, larger-index use <). Vertex contributes
//     w = 1 - #edges_owned + #faces_owned  at bin(x_v): ONE ds_add.
//     (Formulation hardware-verified exact in R3; scaffold proven in R9.)
//   - per (image, 32-row slice) block; 4 rows/thread; 6 rows x (float4 +
//     2 halo scalars) = 18 address-independent loads hoisted upfront.
//   - hist[bin][col] int32 x 32 cols (8 KiB); ds_add fire-and-forget;
//     rotated conflict-free epilogue reduce (R9).
//   - kernel 2: per image, sum 4 slice partials + 64-lane shfl scan -> out.
//   - launch_bounds(256,5): VGPR cap 102.

#define BB 32
#define CC 16
#define HH 128
#define WW 128
#define RESB 64
#define NT 256
#define S 4
#define ROWS (HH / S)    // 32 rows per slice
#define RPT 4            // rows per thread
#define BC (BB * CC)

__device__ __forceinline__ int binq(float F) {
    // F in [0,1): ceil(F*63) lands in [0,63] -- no clamps needed.
    return (int)ceilf(F * 63.0f);
}

__global__ __launch_bounds__(NT, 5) void ecc_hist(const float* __restrict__ X,
                                                  int* __restrict__ ws) {
    __shared__ int hist[RESB * 32];  // [bin][col], 8 KiB
    const int blk = blockIdx.x;
    const int sl = blk & (S - 1);
    const int bc = blk >> 2;  // blk / S
    const int tid = threadIdx.x;
    const int ln = tid & 31;  // lane column
    const float* __restrict__ x = X + (size_t)bc * (HH * WW);

    {
        int4* h4 = (int4*)hist;
        h4[tid] = make_int4(0, 0, 0, 0);
        h4[tid + NT] = make_int4(0, 0, 0, 0);
    }
    __syncthreads();

    const int col4 = tid & 31;   // which float4 of the row
    const int tr = tid >> 5;     // 0..7 thread-row group
    const int r0 = sl * ROWS + tr * RPT;
    const int c0 = col4 * 4;
    const int cL = (c0 > 0) ? c0 - 1 : 0;            // left halo col (k=0 masked)
    const int cR = (c0 + 4 < WW) ? c0 + 4 : WW - 1;  // right halo col (k=3 masked)

    // 6 rows (r0-1 .. r0+4, clamped) x 6 cols (c0-1 .. c0+4), 18 loads upfront.
    float Fr[6][6];
#pragma unroll
    for (int j = 0; j < 6; ++j) {
        int rr = r0 - 1 + j;
        rr = rr < 0 ? 0 : (rr > HH - 1 ? HH - 1 : rr);
        const float* rp = x + rr * WW;
        const float4 a = *(const float4*)(rp + c0);
        Fr[j][1] = a.x; Fr[j][2] = a.y; Fr[j][3] = a.z; Fr[j][4] = a.w;
        Fr[j][0] = rp[cL];
        Fr[j][5] = rp[cR];
    }

    const int hl0 = (col4 > 0) ? 1 : 0;       // k==0 left neighbor exists
    const int hr3 = (col4 < 31) ? 1 : 0;      // k==3 right neighbor exists
    const int hU0 = (r0 > 0) ? 1 : 0;         // dr==0 up row exists
    const int hD3 = (r0 + 3 < HH - 1) ? 1 : 0;// dr==3 down row exists

#pragma unroll
    for (int dr = 0; dr < RPT; ++dr) {
        const int hU = (dr > 0) ? 1 : hU0;  // folds to 1 for dr>0
        const int hD = (dr < 3) ? 1 : hD3;  // folds to 1 for dr<3
#pragma unroll
        for (int k = 0; k < 4; ++k) {
            const int hl = (k > 0) ? 1 : hl0;   // folds for k>0
            const int hr = (k < 3) ? 1 : hr3;   // folds for k<3
            const float xv = Fr[dr + 1][k + 1];
            // ownership predicates (float compares; smaller-index: <=, larger: <)
            const int pL = hl & (Fr[dr + 1][k] <= xv ? 1 : 0);
            const int pR = hr & (Fr[dr + 1][k + 2] < xv ? 1 : 0);
            const int pU = hU & (Fr[dr][k + 1] <= xv ? 1 : 0);
            const int pD = hD & (Fr[dr + 2][k + 1] < xv ? 1 : 0);
            const int fUL = pU & pL & (Fr[dr][k] <= xv ? 1 : 0);
            const int fUR = pU & pR & (Fr[dr][k + 2] <= xv ? 1 : 0);
            const int fDL = pD & pL & (Fr[dr + 2][k] < xv ? 1 : 0);
            const int fDR = pD & pR & (Fr[dr + 2][k + 2] < xv ? 1 : 0);
            const int w = 1 - pL - pR - pU - pD + fUL + fUR + fDL + fDR;
            atomicAdd(&hist[(binq(xv) << 5) + ln], w);  // one ds_add / vertex
        }
    }
    __syncthreads();

    // Reduce over 32 columns: thread (bin = tid&63, q = tid>>6) sums 8,
    // full rotation -> 64 lanes cover all 32 banks (2-way = free).
    const int bin = tid & 63;
    const int q = tid >> 6;
    int ssum = 0;
#pragma unroll
    for (int k = 0; k < 8; ++k) {
        ssum += hist[(bin << 5) + ((q * 8 + bin + k) & 31)];
    }
    __syncthreads();
    hist[tid] = ssum;  // partial at [q*64 + bin]
    __syncthreads();
    if (tid < RESB) {
        ws[blk * RESB + tid] = hist[tid] + hist[tid + 64] + hist[tid + 128] + hist[tid + 192];
    }
}

__global__ __launch_bounds__(64) void ecc_scan(const int* __restrict__ ws,
                                               float* __restrict__ out) {
    const int bc = blockIdx.x;
    const int b = threadIdx.x;  // bin
    int v = 0;
#pragma unroll
    for (int si = 0; si < S; ++si) v += ws[(bc * S + si) * RESB + b];
    // Inclusive prefix scan over 64 lanes (= 64 bins) -> cumsum.
#pragma unroll
    for (int d = 1; d < 64; d <<= 1) {
        const int up = __shfl_up(v, d, 64);
        if (b >= d) v += up;
    }
    out[bc * RESB + b] = (float)v;
}

extern "C" void kernel_launch(void* const* d_in, const int* in_sizes, int n_in,
                              void* d_out, int out_size, void* d_ws, size_t ws_size,
                              hipStream_t stream) {
    const float* x = (const float*)d_in[0];
    float* out = (float*)d_out;
    int* ws = (int*)d_ws;  // BC*S*RESB ints = 512 KiB
    ecc_hist<<<BC * S, NT, 0, stream>>>(x, ws);
    ecc_scan<<<BC, 64, 0, stream>>>(ws, out);
}

// Round 13
// 13.888 us; speedup vs baseline: 1.2018x; 1.2018x over previous
//
#include <hip/hip_runtime.h>

// Euler characteristic curve of sublevel cubical complex.
// x: [B,C,H,W] f32 -> out: [B,C,RES] f32.
//
// R9 structure (proven 13.8us best), single change: launch_bounds(256,5->6).
//   Hist kernel is latency-bound (throughput model: LDS ~1.7us + VALU ~3us +
//   L3 fetch ~3us << 10.5us measured) -> more waves = more latency hiding.
//   (256,6): VGPR cap 85 (est. live peak 65-75, should not spill; the bad
//   case was (256,8)'s 64-cap), 24 waves/CU vs 20.
//   R11 post-mortem: single-dispatch last-block fusion is impossible without
//   an init node (counter mod-S test breaks for unknown/poisoned init) --
//   2-kernel structure retained.
//
//   - per (image, 32-row slice) block; 4 rows/thread; all 10 loads hoisted
//     (5 float4 + 5 halo scalars) -> single vmem-latency stall, max MLP.
//   - branchless 4-atomic per vertex into hist[bin][col] int32 x 32 cols
//     (8 KiB LDS; ds_add fire-and-forget; 2 lanes/bank = free aliasing);
//     edge/face bins via integer max (bin monotone: bin(max)=max(bin)).
//   - rotated conflict-free epilogue reduce; kernel 2: sum 4 partials +
//     64-lane shfl inclusive scan -> out.

#define BB 32
#define CC 16
#define HH 128
#define WW 128
#define RESB 64
#define NT 256
#define S 4
#define ROWS (HH / S)    // 32 rows per slice
#define RPT 4            // rows per thread
#define BC (BB * CC)

__device__ __forceinline__ int binq(float F) {
    // F in [0,1): ceil(F*63) lands in [0,63] -- no clamps needed.
    return (int)ceilf(F * 63.0f);
}

__global__ __launch_bounds__(NT, 6) void ecc_hist(const float* __restrict__ X,
                                                  int* __restrict__ ws) {
    __shared__ int hist[RESB * 32];  // [bin][col], 8 KiB
    const int blk = blockIdx.x;
    const int sl = blk & (S - 1);
    const int bc = blk >> 2;  // blk / S
    const int tid = threadIdx.x;
    const int ln = tid & 31;  // lane column
    const float* __restrict__ x = X + (size_t)bc * (HH * WW);

    {
        int4* h4 = (int4*)hist;
        h4[tid] = make_int4(0, 0, 0, 0);
        h4[tid + NT] = make_int4(0, 0, 0, 0);
    }
    __syncthreads();

    const int col4 = tid & 31;   // which float4 of the row
    const int tr = tid >> 5;     // 0..7 thread-row group
    const int r0 = sl * ROWS + tr * RPT;
    const int c0 = col4 * 4;
    const int cR = (col4 < 31) ? c0 + 4 : WW - 1;     // right halo col (k=3 masked)
    const int r4c = (r0 + 4 < HH) ? r0 + 4 : HH - 1;  // down halo row (clamped; masked)

    // All 10 loads upfront -- address-independent, maximal MLP.
    const float4 R0 = *(const float4*)(x + (r0 + 0) * WW + c0);
    const float4 R1 = *(const float4*)(x + (r0 + 1) * WW + c0);
    const float4 R2 = *(const float4*)(x + (r0 + 2) * WW + c0);
    const float4 R3 = *(const float4*)(x + (r0 + 3) * WW + c0);
    const float4 R4v = *(const float4*)(x + r4c * WW + c0);
    const float H0 = x[(r0 + 0) * WW + cR];
    const float H1 = x[(r0 + 1) * WW + cR];
    const float H2 = x[(r0 + 2) * WW + cR];
    const float H3 = x[(r0 + 3) * WW + cR];
    const float H4 = x[r4c * WW + cR];

    int bn[5][5];
    bn[0][0] = binq(R0.x); bn[0][1] = binq(R0.y); bn[0][2] = binq(R0.z); bn[0][3] = binq(R0.w); bn[0][4] = binq(H0);
    bn[1][0] = binq(R1.x); bn[1][1] = binq(R1.y); bn[1][2] = binq(R1.z); bn[1][3] = binq(R1.w); bn[1][4] = binq(H1);
    bn[2][0] = binq(R2.x); bn[2][1] = binq(R2.y); bn[2][2] = binq(R2.z); bn[2][3] = binq(R2.w); bn[2][4] = binq(H2);
    bn[3][0] = binq(R3.x); bn[3][1] = binq(R3.y); bn[3][2] = binq(R3.z); bn[3][3] = binq(R3.w); bn[3][4] = binq(H3);
    bn[4][0] = binq(R4v.x); bn[4][1] = binq(R4v.y); bn[4][2] = binq(R4v.z); bn[4][3] = binq(R4v.w); bn[4][4] = binq(H4);

    // Only the last owned row (r0+3) can touch the image boundary (r0+3 = 127).
    const int hD3 = (r0 + 3 < HH - 1) ? 1 : 0;

#pragma unroll
    for (int dr = 0; dr < RPT; ++dr) {
        const int hD = (dr < 3) ? 1 : hD3;  // compile-time 1 for dr<3
#pragma unroll
        for (int k = 0; k < 4; ++k) {
            const int hR = (k < 3) ? 1 : ((col4 < 31) ? 1 : 0);  // folds for k<3
            const int u00 = bn[dr][k];
            const int bh  = max(u00, bn[dr][k + 1]);
            const int bvv = max(u00, bn[dr + 1][k]);
            const int bf  = max(bh, max(bn[dr + 1][k], bn[dr + 1][k + 1]));
            atomicAdd(&hist[(u00 << 5) + ln], 1);          // vertex +
            atomicAdd(&hist[(bh  << 5) + ln], -hR);        // h-edge -
            atomicAdd(&hist[(bvv << 5) + ln], -hD);        // v-edge -
            atomicAdd(&hist[(bf  << 5) + ln], hR & hD);    // face  +
        }
    }
    __syncthreads();

    // Reduce over 32 columns: thread (bin = tid&63, q = tid>>6) sums 8,
    // full rotation -> 64 lanes cover all 32 banks (2-way = free).
    const int bin = tid & 63;
    const int q = tid >> 6;
    int ssum = 0;
#pragma unroll
    for (int k = 0; k < 8; ++k) {
        ssum += hist[(bin << 5) + ((q * 8 + bin + k) & 31)];
    }
    __syncthreads();
    hist[tid] = ssum;  // partial at [q*64 + bin]
    __syncthreads();
    if (tid < RESB) {
        ws[blk * RESB + tid] = hist[tid] + hist[tid + 64] + hist[tid + 128] + hist[tid + 192];
    }
}

__global__ __launch_bounds__(64) void ecc_scan(const int* __restrict__ ws,
                                               float* __restrict__ out) {
    const int bc = blockIdx.x;
    const int b = threadIdx.x;  // bin
    int v = 0;
#pragma unroll
    for (int si = 0; si < S; ++si) v += ws[(bc * S + si) * RESB + b];
    // Inclusive prefix scan over 64 lanes (= 64 bins) -> cumsum.
#pragma unroll
    for (int d = 1; d < 64; d <<= 1) {
        const int up = __shfl_up(v, d, 64);
        if (b >= d) v += up;
    }
    out[bc * RESB + b] = (float)v;
}

extern "C" void kernel_launch(void* const* d_in, const int* in_sizes, int n_in,
                              void* d_out, int out_size, void* d_ws, size_t ws_size,
                              hipStream_t stream) {
    const float* x = (const float*)d_in[0];
    float* out = (float*)d_out;
    int* ws = (int*)d_ws;  // BC*S*RESB ints = 512 KiB
    ecc_hist<<<BC * S, NT, 0, stream>>>(x, ws);
    ecc_scan<<<BC, 64, 0, stream>>>(ws, out);
}